// Round 4
// baseline (640.220 us; speedup 1.0000x reference)
//
#include <hip/hip_runtime.h>
#include <stdint.h>

#define D_ 1024
#define H_ 16
#define HD_ 64
#define FF_ 4096
#define T_ 4096
#define TC_ 4097
#define NCH_ 33
#define LAYERS_ 8

// ws layout (floats)
#define WS_QKV 0          // [3072]  q,k,v accum
#define WS_GU 3072        // [8192]  g,u accum
#define WS_HID 11264      // [1024]  residual stream (f32)
#define WS_PART 12288     // [16*33*66] attention partials (m, s, o[64])
#define WS_OH 47136       // [1024]  combined attention head outputs

static constexpr float SCALE_ = 0.49497474683058327f; // 1.4/sqrt(8)
static constexpr float EPS_ = 1e-5f;

__global__ void k_zero(float* __restrict__ p, int n) {
    int i = blockIdx.x * 256 + threadIdx.x;
    if (i < n) p[i] = 0.f;
}

__global__ void k_init(const float* __restrict__ embed, float* __restrict__ hid) {
    int t = threadIdx.x;
    ((float4*)hid)[t] = ((const float4*)embed)[t];
}

// out[z*NCOLS + cols] += (rms(hidden)*lnw) @ Wz ; Wz row-major [1024 x NCOLS]
// grid: (NCOLS/256, 1024/64, nmat); block 256
template<int NCOLS>
__global__ void k_rms_gemv(const float* __restrict__ hidden,
                           const float* __restrict__ lnw,
                           const float* __restrict__ W0,
                           const float* __restrict__ W1,
                           const float* __restrict__ W2,
                           float* __restrict__ out)
{
    int t = threadIdx.x;
    __shared__ float hn[D_];
    __shared__ float wred[4];
    float4 hv = ((const float4*)hidden)[t];
    float ssq = hv.x*hv.x + hv.y*hv.y + hv.z*hv.z + hv.w*hv.w;
    #pragma unroll
    for (int off = 32; off; off >>= 1) ssq += __shfl_down(ssq, off, 64);
    if ((t & 63) == 0) wred[t >> 6] = ssq;
    __syncthreads();
    float rms = rsqrtf((wred[0] + wred[1] + wred[2] + wred[3]) * (1.0f / D_) + EPS_);
    float4 lw = ((const float4*)lnw)[t];
    hn[4*t+0] = hv.x * rms * lw.x;
    hn[4*t+1] = hv.y * rms * lw.y;
    hn[4*t+2] = hv.z * rms * lw.z;
    hn[4*t+3] = hv.w * rms * lw.w;
    __syncthreads();

    const float* W = (blockIdx.z == 0) ? W0 : (blockIdx.z == 1 ? W1 : W2);
    float* outz = out + (size_t)blockIdx.z * NCOLS;
    int colbase = blockIdx.x * 256;
    int rowbase = blockIdx.y * 64;
    int c4 = (t & 63);
    int rg = (t >> 6);
    const float* Wp = W + (size_t)(rowbase + rg*16) * NCOLS + colbase + c4*4;
    float4 acc = make_float4(0.f, 0.f, 0.f, 0.f);
    #pragma unroll
    for (int r = 0; r < 16; ++r) {
        float hs = hn[rowbase + rg*16 + r];
        float4 w4 = *(const float4*)(Wp + (size_t)r * NCOLS);
        acc.x += hs * w4.x; acc.y += hs * w4.y; acc.z += hs * w4.z; acc.w += hs * w4.w;
    }
    __shared__ float4 red4[256];
    red4[t] = acc;
    __syncthreads();
    if (t < 64) {
        float4 a = red4[t], b = red4[t+64], c = red4[t+128], d = red4[t+192];
        float* dst = outz + colbase + t*4;
        atomicAdd(dst+0, a.x+b.x+c.x+d.x);
        atomicAdd(dst+1, a.y+b.y+c.y+d.y);
        atomicAdd(dst+2, a.z+b.z+c.z+d.z);
        atomicAdd(dst+3, a.w+b.w+c.w+d.w);
    }
}

// flash-decode chunk: grid (NCH_, H_); block 256.
// Softmax within chunk serial on thread 0 (correctness-first).
// Also writes f32 K/V cache output copies (rows < T from f32 cache, row T from new roped k / new v).
__global__ void k_attn(const float* __restrict__ kcache,
                       const float* __restrict__ vcache,
                       const float* __restrict__ qkv,   // q@0, k@1024, v@2048
                       const int* __restrict__ posp,
                       float* __restrict__ kc_out,
                       float* __restrict__ vc_out,
                       float* __restrict__ part)
{
    int c = blockIdx.x, h = blockIdx.y, t = threadIdx.x;
    __shared__ float qr[64], kr[64];
    __shared__ float sc[128];
    __shared__ float red[256];
    if (t < 32) {
        float pos = (float)(*posp);
        float inv = expf(-(float)t * (9.210340371976184f / 32.0f)); // 10000^(-t/32)
        float ang = pos * inv;
        float cs = cosf(ang), sn = sinf(ang);
        float q1 = qkv[h*64 + t], q2 = qkv[h*64 + t + 32];
        qr[t] = q1*cs - q2*sn; qr[t+32] = q1*sn + q2*cs;
        float k1 = qkv[1024 + h*64 + t], k2 = qkv[1024 + h*64 + t + 32];
        kr[t] = k1*cs - k2*sn; kr[t+32] = k1*sn + k2*cs;
    }
    __syncthreads();
    int kstart = c * 128;
    int nk = min(128, TC_ - kstart);
    // pass A: scores + f32 K copy. 16 lanes per key, float4 dims.
    int dsub = (t & 15) * 4;
    int kl0 = (t >> 4);
    float4 qv = *(const float4*)&qr[dsub];
    for (int kl = kl0; kl < nk; kl += 16) {
        int key = kstart + kl;
        float4 kv;
        if (key < T_) kv = *(const float4*)(kcache + ((size_t)h*T_ + key)*HD_ + dsub);
        else          kv = *(const float4*)&kr[dsub];
        float p = qv.x*kv.x + qv.y*kv.y + qv.z*kv.z + qv.w*kv.w;
        p += __shfl_down(p, 8, 16);
        p += __shfl_down(p, 4, 16);
        p += __shfl_down(p, 2, 16);
        p += __shfl_down(p, 1, 16);
        if ((t & 15) == 0) sc[kl] = p * 0.125f;
        *(float4*)(kc_out + ((size_t)h*TC_ + key)*HD_ + dsub) = kv;
    }
    __syncthreads();
    // serial softmax on thread 0: max, exp, sum (writes weights into sc)
    if (t == 0) {
        float m = -INFINITY;
        for (int j = 0; j < nk; ++j) m = fmaxf(m, sc[j]);
        float s = 0.f;
        for (int j = 0; j < nk; ++j) { float e = __expf(sc[j] - m); sc[j] = e; s += e; }
        float* pb = part + ((size_t)h*NCH_ + c)*66;
        pb[0] = m; pb[1] = s;
    }
    __syncthreads();
    // pass B: o_c = sum_t w_t * V_t  + f32 V copy. dim = t&63, key group = t>>6.
    int dim = t & 63, kg = t >> 6;
    float acc = 0.f;
    int klend = min(nk, kg*32 + 32);
    for (int kl = kg*32; kl < klend; ++kl) {
        int key = kstart + kl;
        float v;
        if (key < T_) v = vcache[((size_t)h*T_ + key)*HD_ + dim];
        else          v = qkv[2048 + h*64 + dim];
        acc += sc[kl] * v;
        vc_out[((size_t)h*TC_ + key)*HD_ + dim] = v;
    }
    red[t] = acc;
    __syncthreads();
    if (t < 64) {
        float o = red[t] + red[t+64] + red[t+128] + red[t+192];
        part[((size_t)h*NCH_ + c)*66 + 2 + t] = o;
    }
}

// cross-chunk combine: grid(16), block(64); thread = one dim.
__global__ void k_combine(const float* __restrict__ part, float* __restrict__ oh) {
    int h = blockIdx.x, d = threadIdx.x;
    const float* pb = part + (size_t)h * NCH_ * 66;
    float M = -INFINITY;
    for (int c = 0; c < NCH_; ++c) M = fmaxf(M, pb[c*66]);
    float S = 0.f, O = 0.f;
    for (int c = 0; c < NCH_; ++c) {
        float e = __expf(pb[c*66] - M);
        S += pb[c*66 + 1] * e;
        O += pb[c*66 + 2 + d] * e;
    }
    oh[h*64 + d] = O / S;
}

// gemv Wo rows of head=blockIdx.y; hidden += SCALE*partial. grid (4, 16); block 256.
__global__ void k_wo(const float* __restrict__ oh_all,
                     const float* __restrict__ Wo,
                     float* __restrict__ hidden)
{
    int h = blockIdx.y, t = threadIdx.x;
    __shared__ float oh[64];
    if (t < 64) oh[t] = oh_all[h*64 + t];
    __syncthreads();
    int colbase = blockIdx.x * 256;
    int c4 = t & 63, rg = t >> 6;
    const float* Wp = Wo + (size_t)(h*64 + rg*16) * D_ + colbase + c4*4;
    float4 acc = make_float4(0.f, 0.f, 0.f, 0.f);
    #pragma unroll
    for (int r = 0; r < 16; ++r) {
        float os = oh[rg*16 + r];
        float4 w4 = *(const float4*)(Wp + (size_t)r * D_);
        acc.x += os*w4.x; acc.y += os*w4.y; acc.z += os*w4.z; acc.w += os*w4.w;
    }
    __shared__ float4 red4[256];
    red4[t] = acc;
    __syncthreads();
    if (t < 64) {
        float4 a = red4[t], b = red4[t+64], c = red4[t+128], d = red4[t+192];
        float* dst = hidden + colbase + t*4;
        atomicAdd(dst+0, SCALE_*(a.x+b.x+c.x+d.x));
        atomicAdd(dst+1, SCALE_*(a.y+b.y+c.y+d.y));
        atomicAdd(dst+2, SCALE_*(a.z+b.z+c.z+d.z));
        atomicAdd(dst+3, SCALE_*(a.w+b.w+c.w+d.w));
    }
}

// hidden += SCALE * (silu(g)*u) @ Wd ; grid (4, 64); block 256
__global__ void k_down(const float* __restrict__ gu,
                       const float* __restrict__ Wd,
                       float* __restrict__ hidden)
{
    int t = threadIdx.x;
    __shared__ float act[64];
    int rowbase = blockIdx.y * 64;
    if (t < 64) {
        float g = gu[rowbase + t];
        float u = gu[FF_ + rowbase + t];
        act[t] = g / (1.f + __expf(-g)) * u;
    }
    __syncthreads();
    int colbase = blockIdx.x * 256;
    int c4 = t & 63, rg = t >> 6;
    const float* Wp = Wd + (size_t)(rowbase + rg*16) * D_ + colbase + c4*4;
    float4 acc = make_float4(0.f, 0.f, 0.f, 0.f);
    #pragma unroll
    for (int r = 0; r < 16; ++r) {
        float as = act[rg*16 + r];
        float4 w4 = *(const float4*)(Wp + (size_t)r * D_);
        acc.x += as*w4.x; acc.y += as*w4.y; acc.z += as*w4.z; acc.w += as*w4.w;
    }
    __shared__ float4 red4[256];
    red4[t] = acc;
    __syncthreads();
    if (t < 64) {
        float4 a = red4[t], b = red4[t+64], c = red4[t+128], d = red4[t+192];
        float* dst = hidden + colbase + t*4;
        atomicAdd(dst+0, SCALE_*(a.x+b.x+c.x+d.x));
        atomicAdd(dst+1, SCALE_*(a.y+b.y+c.y+d.y));
        atomicAdd(dst+2, SCALE_*(a.z+b.z+c.z+d.z));
        atomicAdd(dst+3, SCALE_*(a.w+b.w+c.w+d.w));
    }
}

__global__ void k_final(const float* __restrict__ hidden,
                        const float* __restrict__ nw,
                        float* __restrict__ out)
{
    int t = threadIdx.x;
    __shared__ float wred[4];
    float4 hv = ((const float4*)hidden)[t];
    float ssq = hv.x*hv.x + hv.y*hv.y + hv.z*hv.z + hv.w*hv.w;
    #pragma unroll
    for (int off = 32; off; off >>= 1) ssq += __shfl_down(ssq, off, 64);
    if ((t & 63) == 0) wred[t >> 6] = ssq;
    __syncthreads();
    float rms = rsqrtf((wred[0] + wred[1] + wred[2] + wred[3]) * (1.0f / D_) + EPS_);
    float4 w = ((const float4*)nw)[t];
    float4 ob;
    ob.x = hv.x * rms * w.x;
    ob.y = hv.y * rms * w.y;
    ob.z = hv.z * rms * w.z;
    ob.w = hv.w * rms * w.w;
    ((float4*)out)[t] = ob;
}

// role indices: 0 embed, 1+2i k_i, 2+2i v_i (i<8), 17 ln1, 18 ln2, 19 norm,
//               20 Wq, 21 Wk, 22 Wv, 23 Wo, 24 Wg, 25 Wu, 26 Wd, 27 pos
static const int ROLE_SIZES[28] = {
    1024,
    4194304,4194304,4194304,4194304,4194304,4194304,4194304,4194304,
    4194304,4194304,4194304,4194304,4194304,4194304,4194304,4194304,
    8192, 8192, 1024,
    8388608, 8388608, 8388608, 8388608,
    33554432, 33554432, 33554432,
    1
};

extern "C" void kernel_launch(void* const* d_in, const int* in_sizes, int n_in,
                              void* d_out, int out_size, void* d_ws, size_t ws_size,
                              hipStream_t stream)
{
    int perm[28];
    bool matched = false;

    auto try_perm = [&](const int* cand) {
        if (matched) return;
        for (int r = 0; r < 28; ++r)
            if (in_sizes[cand[r]] != ROLE_SIZES[r]) return;
        for (int r = 0; r < 28; ++r) perm[r] = cand[r];
        matched = true;
    };

    {   // C0 documented dict order
        int c[28];
        for (int r = 0; r < 28; ++r) c[r] = r;
        try_perm(c);
    }
    {   // C1 signature order: embed, position, k0,v0..k7,v7, ln1, ln2, norm, Wq..Wd
        int c[28];
        c[0]=0; c[27]=1;
        for (int i = 0; i < 8; ++i) { c[1+2*i]=2+2*i; c[2+2*i]=3+2*i; }
        c[17]=18; c[18]=19; c[19]=20;
        c[20]=21; c[21]=22; c[22]=23; c[23]=24; c[24]=25; c[25]=26; c[26]=27;
        try_perm(c);
    }
    {   // C2 name-sorted: Wd,Wg,Wk,Wo,Wq,Wu,Wv,embed,k0..k7,ln1,ln2,norm,position,v0..v7
        int c[28];
        c[26]=0; c[24]=1; c[21]=2; c[23]=3; c[20]=4; c[25]=5; c[22]=6; c[0]=7;
        for (int i = 0; i < 8; ++i) c[1+2*i] = 8+i;
        c[17]=16; c[18]=17; c[19]=18; c[27]=19;
        for (int i = 0; i < 8; ++i) c[2+2*i] = 20+i;
        try_perm(c);
    }
    {   // C3 size-asc stable
        int c[28];
        c[27]=0; c[0]=1; c[19]=2; c[17]=3; c[18]=4;
        for (int i = 0; i < 8; ++i) { c[1+2*i]=5+2*i; c[2+2*i]=6+2*i; }
        c[20]=21; c[21]=22; c[22]=23; c[23]=24; c[24]=25; c[25]=26; c[26]=27;
        try_perm(c);
    }
    {   // C4 size-desc stable
        int c[28];
        c[24]=0; c[25]=1; c[26]=2; c[20]=3; c[21]=4; c[22]=5; c[23]=6;
        for (int i = 0; i < 8; ++i) { c[1+2*i]=7+2*i; c[2+2*i]=8+2*i; }
        c[17]=23; c[18]=24; c[0]=25; c[19]=26; c[27]=27;
        try_perm(c);
    }
    {   // C5 reversed dict
        int c[28];
        c[27]=0; c[26]=1; c[25]=2; c[24]=3; c[23]=4; c[22]=5; c[21]=6; c[20]=7;
        c[19]=8; c[18]=9; c[17]=10;
        for (int j = 0; j < 8; ++j) { c[2+2*(7-j)]=11+2*j; c[1+2*(7-j)]=12+2*j; }
        c[0]=27;
        try_perm(c);
    }
    if (!matched) { for (int r = 0; r < 28; ++r) perm[r] = r; }

    const float* embed = (const float*)d_in[perm[0]];
    const float* kcs[LAYERS_];
    const float* vcs[LAYERS_];
    for (int i = 0; i < LAYERS_; ++i) {
        kcs[i] = (const float*)d_in[perm[1+2*i]];
        vcs[i] = (const float*)d_in[perm[2+2*i]];
    }
    const float* ln1 = (const float*)d_in[perm[17]];
    const float* ln2 = (const float*)d_in[perm[18]];
    const float* nw  = (const float*)d_in[perm[19]];
    const float* Wq  = (const float*)d_in[perm[20]];
    const float* Wk  = (const float*)d_in[perm[21]];
    const float* Wv  = (const float*)d_in[perm[22]];
    const float* Wo  = (const float*)d_in[perm[23]];
    const float* Wg  = (const float*)d_in[perm[24]];
    const float* Wu  = (const float*)d_in[perm[25]];
    const float* Wd  = (const float*)d_in[perm[26]];
    const int*   pos = (const int*)d_in[perm[27]];

    float* out = (float*)d_out;   // f32 outputs (reference output dtype is float32)
    float* ws = (float*)d_ws;
    float* accQKV = ws + WS_QKV;
    float* accGU  = ws + WS_GU;
    float* hid    = ws + WS_HID;
    float* part   = ws + WS_PART;
    float* ohbuf  = ws + WS_OH;

    (void)out_size; (void)ws_size; (void)n_in;

    k_init<<<1, 256, 0, stream>>>(embed, hid);

    const size_t KVSZ = (size_t)H_ * TC_ * HD_; // 4,195,328
    for (int i = 0; i < LAYERS_; ++i) {
        float* kco = out + 1024 + (size_t)i * 2 * KVSZ;
        float* vco = kco + KVSZ;

        k_zero<<<44, 256, 0, stream>>>(ws, WS_HID);  // accQKV + accGU

        k_rms_gemv<D_><<<dim3(4, 16, 3), 256, 0, stream>>>(
            hid, ln1 + i*D_,
            Wq + (size_t)i*D_*D_, Wk + (size_t)i*D_*D_, Wv + (size_t)i*D_*D_,
            accQKV);

        k_attn<<<dim3(NCH_, H_), 256, 0, stream>>>(kcs[i], vcs[i], accQKV, pos, kco, vco, part);

        k_combine<<<16, 64, 0, stream>>>(part, ohbuf);

        k_wo<<<dim3(4, 16), 256, 0, stream>>>(ohbuf, Wo + (size_t)i*D_*D_, hid);

        k_rms_gemv<FF_><<<dim3(16, 16, 2), 256, 0, stream>>>(
            hid, ln2 + i*D_,
            Wg + (size_t)i*D_*FF_, Wu + (size_t)i*D_*FF_, nullptr,
            accGU);

        k_down<<<dim3(4, 64), 256, 0, stream>>>(accGU, Wd + (size_t)i*FF_*D_, hid);
    }
    k_final<<<1, 256, 0, stream>>>(hid, nw, out);
}

// Round 5
// 564.954 us; speedup vs baseline: 1.1332x; 1.1332x over previous
//
#include <hip/hip_runtime.h>
#include <stdint.h>

#define D_ 1024
#define H_ 16
#define HD_ 64
#define FF_ 4096
#define T_ 4096
#define TC_ 4097
#define CHUNK_ 64
#define NCH_ 65
#define LAYERS_ 8

// ws layout (floats)
#define WS_QKV 0          // [3072]  q,k,v accum (zeroed by k_init / k_down block(0,0))
#define WS_GU 3072        // [8192]  g,u accum  (zeroed by k_wo block(0,0))
#define WS_HID 11264      // [1024]  residual stream (f32)
#define WS_PART 12288     // [16*65*66 = 68640] attention partials (m, s, o[64])

static constexpr float SCALE_ = 0.49497474683058327f; // 1.4/sqrt(8)
static constexpr float EPS_ = 1e-5f;

__global__ void k_init(const float* __restrict__ embed, float* __restrict__ hid,
                       float* __restrict__ accQKV) {
    int t = threadIdx.x;
    ((float4*)hid)[t] = ((const float4*)embed)[t];
    for (int i = t; i < 3072; i += 256) accQKV[i] = 0.f;
}

// out[z*NCOLS + coltile] += (rms(hidden)*lnw) @ Wz ; Wz row-major [1024 x NCOLS]
// grid: (NCOLS/64, 1024/64, nmat); block 256. Each block: 64 rows x 64 cols.
template<int NCOLS>
__global__ void k_rms_gemv(const float* __restrict__ hidden,
                           const float* __restrict__ lnw,
                           const float* __restrict__ W0,
                           const float* __restrict__ W1,
                           const float* __restrict__ W2,
                           float* __restrict__ out)
{
    int t = threadIdx.x;
    __shared__ float hn[D_];
    __shared__ float wred[4];
    float4 hv = ((const float4*)hidden)[t];
    float ssq = hv.x*hv.x + hv.y*hv.y + hv.z*hv.z + hv.w*hv.w;
    #pragma unroll
    for (int off = 32; off; off >>= 1) ssq += __shfl_down(ssq, off, 64);
    if ((t & 63) == 0) wred[t >> 6] = ssq;
    __syncthreads();
    float rms = rsqrtf((wred[0] + wred[1] + wred[2] + wred[3]) * (1.0f / D_) + EPS_);
    float4 lw = ((const float4*)lnw)[t];
    hn[4*t+0] = hv.x * rms * lw.x;
    hn[4*t+1] = hv.y * rms * lw.y;
    hn[4*t+2] = hv.z * rms * lw.z;
    hn[4*t+3] = hv.w * rms * lw.w;
    __syncthreads();

    const float* W = (blockIdx.z == 0) ? W0 : (blockIdx.z == 1 ? W1 : W2);
    float* outz = out + (size_t)blockIdx.z * NCOLS;
    int colbase = blockIdx.x * 64;
    int rowbase = blockIdx.y * 64;
    int c4 = t & 15;          // 16 x 4 = 64 cols
    int rg = t >> 4;          // 16 row groups x 4 rows = 64 rows
    int row0 = rowbase + rg*4;
    const float* Wp = W + (size_t)row0 * NCOLS + colbase + c4*4;
    float4 acc = make_float4(0.f, 0.f, 0.f, 0.f);
    #pragma unroll
    for (int r = 0; r < 4; ++r) {
        float hs = hn[row0 + r];
        float4 w4 = *(const float4*)(Wp + (size_t)r * NCOLS);
        acc.x += hs * w4.x; acc.y += hs * w4.y; acc.z += hs * w4.z; acc.w += hs * w4.w;
    }
    __shared__ float4 red4[256];
    red4[t] = acc;
    __syncthreads();
    if (t < 16) {
        float4 s = red4[t];
        #pragma unroll
        for (int g = 1; g < 16; ++g) {
            float4 r4 = red4[t + 16*g];
            s.x += r4.x; s.y += r4.y; s.z += r4.z; s.w += r4.w;
        }
        float* dst = outz + colbase + t*4;
        atomicAdd(dst+0, s.x);
        atomicAdd(dst+1, s.y);
        atomicAdd(dst+2, s.z);
        atomicAdd(dst+3, s.w);
    }
}

// flash-decode chunk (64 keys): grid (NCH_, H_); block 256.
// Serial chunk softmax on thread 0 (matches passing round 4 numerics).
// Writes f32 K/V cache output copies (rows < T from f32 cache, row T = roped k / new v).
__global__ void k_attn(const float* __restrict__ kcache,
                       const float* __restrict__ vcache,
                       const float* __restrict__ qkv,   // q@0, k@1024, v@2048
                       const int* __restrict__ posp,
                       float* __restrict__ kc_out,
                       float* __restrict__ vc_out,
                       float* __restrict__ part)
{
    int c = blockIdx.x, h = blockIdx.y, t = threadIdx.x;
    __shared__ float qr[64], kr[64];
    __shared__ float sc[CHUNK_];
    __shared__ float red[256];
    if (t < 32) {
        float pos = (float)(*posp);
        float inv = expf(-(float)t * (9.210340371976184f / 32.0f)); // 10000^(-t/32)
        float ang = pos * inv;
        float cs = cosf(ang), sn = sinf(ang);
        float q1 = qkv[h*64 + t], q2 = qkv[h*64 + t + 32];
        qr[t] = q1*cs - q2*sn; qr[t+32] = q1*sn + q2*cs;
        float k1 = qkv[1024 + h*64 + t], k2 = qkv[1024 + h*64 + t + 32];
        kr[t] = k1*cs - k2*sn; kr[t+32] = k1*sn + k2*cs;
    }
    __syncthreads();
    int kstart = c * CHUNK_;
    int nk = min(CHUNK_, TC_ - kstart);
    // pass A: scores + f32 K copy. 16 lanes per key, float4 dims.
    int dsub = (t & 15) * 4;
    int kl0 = (t >> 4);
    float4 qv = *(const float4*)&qr[dsub];
    for (int kl = kl0; kl < nk; kl += 16) {
        int key = kstart + kl;
        float4 kv;
        if (key < T_) kv = *(const float4*)(kcache + ((size_t)h*T_ + key)*HD_ + dsub);
        else          kv = *(const float4*)&kr[dsub];
        float p = qv.x*kv.x + qv.y*kv.y + qv.z*kv.z + qv.w*kv.w;
        p += __shfl_down(p, 8, 16);
        p += __shfl_down(p, 4, 16);
        p += __shfl_down(p, 2, 16);
        p += __shfl_down(p, 1, 16);
        if ((t & 15) == 0) sc[kl] = p * 0.125f;
        *(float4*)(kc_out + ((size_t)h*TC_ + key)*HD_ + dsub) = kv;
    }
    __syncthreads();
    // serial softmax on thread 0: max, exp, sum (writes weights into sc)
    if (t == 0) {
        float m = -INFINITY;
        for (int j = 0; j < nk; ++j) m = fmaxf(m, sc[j]);
        float s = 0.f;
        for (int j = 0; j < nk; ++j) { float e = __expf(sc[j] - m); sc[j] = e; s += e; }
        float* pb = part + ((size_t)h*NCH_ + c)*66;
        pb[0] = m; pb[1] = s;
    }
    __syncthreads();
    // pass B: o_c = sum_t w_t * V_t + f32 V copy. dim = t&63, key group = t>>6 (4 x 16 keys).
    int dim = t & 63, kg = t >> 6;
    float acc = 0.f;
    int klend = min(nk, kg*16 + 16);
    for (int kl = kg*16; kl < klend; ++kl) {
        int key = kstart + kl;
        float v;
        if (key < T_) v = vcache[((size_t)h*T_ + key)*HD_ + dim];
        else          v = qkv[2048 + h*64 + dim];
        acc += sc[kl] * v;
        vc_out[((size_t)h*TC_ + key)*HD_ + dim] = v;
    }
    red[t] = acc;
    __syncthreads();
    if (t < 64) {
        float o = red[t] + red[t+64] + red[t+128] + red[t+192];
        part[((size_t)h*NCH_ + c)*66 + 2 + t] = o;
    }
}

// combine (per-head, fused) + gemv 64 rows of Wo; hidden += SCALE*partial.
// grid (16, 16): x = coltile(64), y = head. block 256. Block (0,0) zeroes accGU.
__global__ void k_wo(const float* __restrict__ part,
                     const float* __restrict__ Wo,
                     float* __restrict__ hidden,
                     float* __restrict__ accGU)
{
    int h = blockIdx.y, t = threadIdx.x;
    if (blockIdx.x == 0 && blockIdx.y == 0) {
        for (int i = t; i < 2*FF_; i += 256) accGU[i] = 0.f;
    }
    __shared__ float oh[64];
    if (t < 64) {
        const float* pb = part + (size_t)h * NCH_ * 66;
        float M = -INFINITY;
        for (int c = 0; c < NCH_; ++c) M = fmaxf(M, pb[c*66]);
        float S = 0.f, O = 0.f;
        for (int c = 0; c < NCH_; ++c) {
            float e = __expf(pb[c*66] - M);
            S += pb[c*66 + 1] * e;
            O += pb[c*66 + 2 + t] * e;
        }
        oh[t] = O / S;
    }
    __syncthreads();
    int colbase = blockIdx.x * 64;
    int c4 = t & 15, rg = t >> 4;
    int row0 = rg*4;
    const float* Wp = Wo + (size_t)(h*64 + row0) * D_ + colbase + c4*4;
    float4 acc = make_float4(0.f, 0.f, 0.f, 0.f);
    #pragma unroll
    for (int r = 0; r < 4; ++r) {
        float os = oh[row0 + r];
        float4 w4 = *(const float4*)(Wp + (size_t)r * D_);
        acc.x += os*w4.x; acc.y += os*w4.y; acc.z += os*w4.z; acc.w += os*w4.w;
    }
    __shared__ float4 red4[256];
    red4[t] = acc;
    __syncthreads();
    if (t < 16) {
        float4 s = red4[t];
        #pragma unroll
        for (int g = 1; g < 16; ++g) {
            float4 r4 = red4[t + 16*g];
            s.x += r4.x; s.y += r4.y; s.z += r4.z; s.w += r4.w;
        }
        float* dst = hidden + colbase + t*4;
        atomicAdd(dst+0, SCALE_*s.x);
        atomicAdd(dst+1, SCALE_*s.y);
        atomicAdd(dst+2, SCALE_*s.z);
        atomicAdd(dst+3, SCALE_*s.w);
    }
}

// hidden += SCALE * (silu(g)*u) @ Wd ; grid (16, 64): x = coltile(64), y = rowgroup(64 of 4096).
// block 256. Block (0,0) zeroes accQKV for the next layer.
__global__ void k_down(const float* __restrict__ gu,
                       const float* __restrict__ Wd,
                       float* __restrict__ hidden,
                       float* __restrict__ accQKV)
{
    int t = threadIdx.x;
    if (blockIdx.x == 0 && blockIdx.y == 0) {
        for (int i = t; i < 3072; i += 256) accQKV[i] = 0.f;
    }
    __shared__ float act[64];
    int rowbase = blockIdx.y * 64;
    if (t < 64) {
        float g = gu[rowbase + t];
        float u = gu[FF_ + rowbase + t];
        act[t] = g / (1.f + __expf(-g)) * u;
    }
    __syncthreads();
    int colbase = blockIdx.x * 64;
    int c4 = t & 15, rg = t >> 4;
    int row0 = rg*4;
    const float* Wp = Wd + (size_t)(rowbase + row0) * D_ + colbase + c4*4;
    float4 acc = make_float4(0.f, 0.f, 0.f, 0.f);
    #pragma unroll
    for (int r = 0; r < 4; ++r) {
        float as = act[row0 + r];
        float4 w4 = *(const float4*)(Wp + (size_t)r * D_);
        acc.x += as*w4.x; acc.y += as*w4.y; acc.z += as*w4.z; acc.w += as*w4.w;
    }
    __shared__ float4 red4[256];
    red4[t] = acc;
    __syncthreads();
    if (t < 16) {
        float4 s = red4[t];
        #pragma unroll
        for (int g = 1; g < 16; ++g) {
            float4 r4 = red4[t + 16*g];
            s.x += r4.x; s.y += r4.y; s.z += r4.z; s.w += r4.w;
        }
        float* dst = hidden + colbase + t*4;
        atomicAdd(dst+0, SCALE_*s.x);
        atomicAdd(dst+1, SCALE_*s.y);
        atomicAdd(dst+2, SCALE_*s.z);
        atomicAdd(dst+3, SCALE_*s.w);
    }
}

__global__ void k_final(const float* __restrict__ hidden,
                        const float* __restrict__ nw,
                        float* __restrict__ out)
{
    int t = threadIdx.x;
    __shared__ float wred[4];
    float4 hv = ((const float4*)hidden)[t];
    float ssq = hv.x*hv.x + hv.y*hv.y + hv.z*hv.z + hv.w*hv.w;
    #pragma unroll
    for (int off = 32; off; off >>= 1) ssq += __shfl_down(ssq, off, 64);
    if ((t & 63) == 0) wred[t >> 6] = ssq;
    __syncthreads();
    float rms = rsqrtf((wred[0] + wred[1] + wred[2] + wred[3]) * (1.0f / D_) + EPS_);
    float4 w = ((const float4*)nw)[t];
    float4 ob;
    ob.x = hv.x * rms * w.x;
    ob.y = hv.y * rms * w.y;
    ob.z = hv.z * rms * w.z;
    ob.w = hv.w * rms * w.w;
    ((float4*)out)[t] = ob;
}

// role indices: 0 embed, 1+2i k_i, 2+2i v_i (i<8), 17 ln1, 18 ln2, 19 norm,
//               20 Wq, 21 Wk, 22 Wv, 23 Wo, 24 Wg, 25 Wu, 26 Wd, 27 pos
static const int ROLE_SIZES[28] = {
    1024,
    4194304,4194304,4194304,4194304,4194304,4194304,4194304,4194304,
    4194304,4194304,4194304,4194304,4194304,4194304,4194304,4194304,
    8192, 8192, 1024,
    8388608, 8388608, 8388608, 8388608,
    33554432, 33554432, 33554432,
    1
};

extern "C" void kernel_launch(void* const* d_in, const int* in_sizes, int n_in,
                              void* d_out, int out_size, void* d_ws, size_t ws_size,
                              hipStream_t stream)
{
    int perm[28];
    bool matched = false;

    auto try_perm = [&](const int* cand) {
        if (matched) return;
        for (int r = 0; r < 28; ++r)
            if (in_sizes[cand[r]] != ROLE_SIZES[r]) return;
        for (int r = 0; r < 28; ++r) perm[r] = cand[r];
        matched = true;
    };

    {   // C0 documented dict order (this matched in the passing round)
        int c[28];
        for (int r = 0; r < 28; ++r) c[r] = r;
        try_perm(c);
    }
    {   // C1 signature order
        int c[28];
        c[0]=0; c[27]=1;
        for (int i = 0; i < 8; ++i) { c[1+2*i]=2+2*i; c[2+2*i]=3+2*i; }
        c[17]=18; c[18]=19; c[19]=20;
        c[20]=21; c[21]=22; c[22]=23; c[23]=24; c[24]=25; c[25]=26; c[26]=27;
        try_perm(c);
    }
    {   // C2 name-sorted
        int c[28];
        c[26]=0; c[24]=1; c[21]=2; c[23]=3; c[20]=4; c[25]=5; c[22]=6; c[0]=7;
        for (int i = 0; i < 8; ++i) c[1+2*i] = 8+i;
        c[17]=16; c[18]=17; c[19]=18; c[27]=19;
        for (int i = 0; i < 8; ++i) c[2+2*i] = 20+i;
        try_perm(c);
    }
    if (!matched) { for (int r = 0; r < 28; ++r) perm[r] = r; }

    const float* embed = (const float*)d_in[perm[0]];
    const float* kcs[LAYERS_];
    const float* vcs[LAYERS_];
    for (int i = 0; i < LAYERS_; ++i) {
        kcs[i] = (const float*)d_in[perm[1+2*i]];
        vcs[i] = (const float*)d_in[perm[2+2*i]];
    }
    const float* ln1 = (const float*)d_in[perm[17]];
    const float* ln2 = (const float*)d_in[perm[18]];
    const float* nw  = (const float*)d_in[perm[19]];
    const float* Wq  = (const float*)d_in[perm[20]];
    const float* Wk  = (const float*)d_in[perm[21]];
    const float* Wv  = (const float*)d_in[perm[22]];
    const float* Wo  = (const float*)d_in[perm[23]];
    const float* Wg  = (const float*)d_in[perm[24]];
    const float* Wu  = (const float*)d_in[perm[25]];
    const float* Wd  = (const float*)d_in[perm[26]];
    const int*   pos = (const int*)d_in[perm[27]];

    float* out = (float*)d_out;   // f32 outputs
    float* ws = (float*)d_ws;
    float* accQKV = ws + WS_QKV;
    float* accGU  = ws + WS_GU;
    float* hid    = ws + WS_HID;
    float* part   = ws + WS_PART;

    (void)out_size; (void)ws_size; (void)n_in;

    k_init<<<1, 256, 0, stream>>>(embed, hid, accQKV);

    const size_t KVSZ = (size_t)H_ * TC_ * HD_; // 4,195,328
    for (int i = 0; i < LAYERS_; ++i) {
        float* kco = out + 1024 + (size_t)i * 2 * KVSZ;
        float* vco = kco + KVSZ;

        k_rms_gemv<D_><<<dim3(16, 16, 3), 256, 0, stream>>>(
            hid, ln1 + i*D_,
            Wq + (size_t)i*D_*D_, Wk + (size_t)i*D_*D_, Wv + (size_t)i*D_*D_,
            accQKV);

        k_attn<<<dim3(NCH_, H_), 256, 0, stream>>>(kcs[i], vcs[i], accQKV, pos, kco, vco, part);

        k_wo<<<dim3(16, 16), 256, 0, stream>>>(part, Wo + (size_t)i*D_*D_, hid, accGU);

        k_rms_gemv<FF_><<<dim3(64, 16, 2), 256, 0, stream>>>(
            hid, ln2 + i*D_,
            Wg + (size_t)i*D_*FF_, Wu + (size_t)i*D_*FF_, nullptr,
            accGU);

        k_down<<<dim3(16, 64), 256, 0, stream>>>(accGU, Wd + (size_t)i*FF_*D_, hid, accQKV);
    }
    k_final<<<1, 256, 0, stream>>>(hid, nw, out);
}